// Round 1
// baseline (24468.752 us; speedup 1.0000x reference)
//
#include <hip/hip_runtime.h>
#include <hip/hip_bf16.h>

#define Bq 4096
#define Nq 17
#define DIMq 512
#define Hq 8
#define HDq 64
#define EPSq 1e-5f

// ws layout (floats):
// [0,289)      A_sym (symmetrized adj+adj2)
// [512,1024)   per-channel sum of graphconv out
// [1024,1536)  per-channel sumsq
// [1536,2048)  BN scale = gamma/sqrt(var+eps)
// [2048,2560)  BN shift = beta - mean*scale

__global__ void k_prep(const float* __restrict__ adj, const float* __restrict__ adj2,
                       float* __restrict__ ws) {
    int t = threadIdx.x;  // 512 threads
    if (t < Nq * Nq) {
        int n = t / Nq, m = t % Nq;
        ws[t] = 0.5f * ((adj[n * Nq + m] + adj2[n * Nq + m]) +
                        (adj[m * Nq + n] + adj2[m * Nq + n]));
    }
    ws[512 + t] = 0.f;   // sum
    ws[1024 + t] = 0.f;  // sumsq
}

__global__ __launch_bounds__(512) void k_stats(
    const float* __restrict__ x, const float* __restrict__ W,
    const float* __restrict__ Mg, const float* __restrict__ gbias,
    float* __restrict__ ws) {
    __shared__ float As[Nq * Nq];
    __shared__ float xs[2 * Nq];
    const int t = threadIdx.x;  // channel o = t
    if (t < Nq * Nq) As[t] = ws[t];
    const float W00 = W[t], W01 = W[DIMq + t], W10 = W[2 * DIMq + t], W11 = W[3 * DIMq + t];
    const float gb = gbias[t];
    float Mr[Nq];
#pragma unroll
    for (int m = 0; m < Nq; m++) Mr[m] = Mg[m * DIMq + t];
    float sum = 0.f, sq = 0.f;
    for (int i = 0; i < 16; i++) {
        int b = blockIdx.x * 16 + i;
        __syncthreads();
        if (t < 2 * Nq) xs[t] = x[b * 2 * Nq + t];
        __syncthreads();
        float u[Nq];
#pragma unroll
        for (int m = 0; m < Nq; m++)
            u[m] = Mr[m] * (xs[2 * m] * W10 + xs[2 * m + 1] * W11);
#pragma unroll
        for (int n = 0; n < Nq; n++) {
            float S = gb;
#pragma unroll
            for (int m = 0; m < Nq; m++) S += As[n * Nq + m] * u[m];
            float dgn = Mr[n] * (xs[2 * n] * W00 + xs[2 * n + 1] * W01);
            float ov = S + As[n * Nq + n] * (dgn - u[n]);
            sum += ov;
            sq += ov * ov;
        }
    }
    atomicAdd(&ws[512 + t], sum);
    atomicAdd(&ws[1024 + t], sq);
}

__global__ void k_finalize(const float* __restrict__ bn_gamma,
                           const float* __restrict__ bn_beta,
                           float* __restrict__ ws) {
    int t = threadIdx.x;  // 512 threads
    const float inv = 1.0f / (float)(Bq * Nq);
    float mean = ws[512 + t] * inv;
    float var = ws[1024 + t] * inv - mean * mean;
    float rstd = 1.0f / sqrtf(var + EPSq);
    float sc = bn_gamma[t] * rstd;
    ws[1536 + t] = sc;
    ws[2048 + t] = bn_beta[t] - mean * sc;
}

__global__ __launch_bounds__(512) void k_main(
    const float* __restrict__ x, const float* __restrict__ W,
    const float* __restrict__ Mg, const float* __restrict__ gbias,
    const float* __restrict__ pos, const float* __restrict__ lng,
    const float* __restrict__ lnb, const float* __restrict__ qkvw,
    const float* __restrict__ projw, const float* __restrict__ projb,
    const float* __restrict__ ws, float* __restrict__ out) {
    __shared__ float As[Nq * Nq];
    __shared__ float xs[2 * Nq];
    __shared__ float xn[Nq][DIMq];
    __shared__ float qs[Nq][HDq + 4];
    __shared__ float ks2[Nq][HDq + 4];
    __shared__ float vs2[Nq][HDq + 4];
    __shared__ float sm[Nq][Nq + 1];
    __shared__ float red[8][2 * Nq];
    __shared__ float stats[2 * Nq];
    __shared__ float muv[Nq], rsv[Nq];
    __shared__ float oh[Nq][HDq + 4];

    const int t = threadIdx.x;  // channel o = t
    const int b = blockIdx.x;
    if (t < Nq * Nq) As[t] = ws[t];
    if (t < 2 * Nq) xs[t] = x[b * 2 * Nq + t];
    const float W00 = W[t], W01 = W[DIMq + t], W10 = W[2 * DIMq + t], W11 = W[3 * DIMq + t];
    const float gb = gbias[t];
    const float bsc = ws[1536 + t], bsh = ws[2048 + t];
    const float lg = lng[t], lb = lnb[t];
    __syncthreads();

    // --- graph conv + BN + relu + pos  (res kept in registers xp[]) ---
    float u[Nq], dg[Nq], xp[Nq];
#pragma unroll
    for (int m = 0; m < Nq; m++) {
        float Mv = Mg[m * DIMq + t];
        float x0 = xs[2 * m], x1 = xs[2 * m + 1];
        u[m] = Mv * (x0 * W10 + x1 * W11);
        dg[m] = Mv * (x0 * W00 + x1 * W01);
    }
#pragma unroll
    for (int n = 0; n < Nq; n++) {
        float S = gb;
#pragma unroll
        for (int m = 0; m < Nq; m++) S += As[n * Nq + m] * u[m];
        float ov = S + As[n * Nq + n] * (dg[n] - u[n]);
        xp[n] = fmaxf(ov * bsc + bsh, 0.f) + pos[n * DIMq + t];
    }

    // --- LayerNorm row stats: reduce xp and xp^2 across 512 threads ---
    const int lane = t & 63, wid = t >> 6;
#pragma unroll
    for (int n = 0; n < Nq; n++) {
        float a = xp[n], q2 = a * a;
#pragma unroll
        for (int off = 32; off; off >>= 1) {
            a += __shfl_xor(a, off);
            q2 += __shfl_xor(q2, off);
        }
        if (lane == 0) {
            red[wid][n] = a;
            red[wid][Nq + n] = q2;
        }
    }
    __syncthreads();
    if (t < 2 * Nq) {
        float s = 0.f;
#pragma unroll
        for (int w = 0; w < 8; w++) s += red[w][t];
        stats[t] = s;
    }
    __syncthreads();
    if (t < Nq) {
        float mu = stats[t] * (1.f / DIMq);
        float var = stats[Nq + t] * (1.f / DIMq) - mu * mu;
        muv[t] = mu;
        rsv[t] = 1.f / sqrtf(var + EPSq);
    }
    __syncthreads();
#pragma unroll
    for (int n = 0; n < Nq; n++)
        xn[n][t] = (xp[n] - muv[n]) * rsv[n] * lg + lb;

    // --- attention, head by head; proj accumulated into registers ---
    float acc[Nq];
#pragma unroll
    for (int n = 0; n < Nq; n++) acc[n] = 0.f;

    for (int h = 0; h < Hq; h++) {
        __syncthreads();  // xn ready (h==0) / buffers free for reuse (h>0)
        // qkv: 3*17*64 outputs, each a K=512 dot
        for (int idx = t; idx < 3 * Nq * HDq; idx += 512) {
            int which = idx / (Nq * HDq);
            int r = idx - which * (Nq * HDq);
            int n = r >> 6, hd = r & 63;
            const float4* wr = reinterpret_cast<const float4*>(qkvw + (size_t)(which * DIMq + h * HDq + hd) * DIMq);
            const float4* xr = reinterpret_cast<const float4*>(&xn[n][0]);
            float s0 = 0.f, s1 = 0.f;
#pragma unroll 8
            for (int c = 0; c < DIMq / 4; c++) {
                float4 a = xr[c], wv = wr[c];
                s0 += a.x * wv.x + a.y * wv.y;
                s1 += a.z * wv.z + a.w * wv.w;
            }
            float s = s0 + s1;
            if (which == 0) qs[n][hd] = s;
            else if (which == 1) ks2[n][hd] = s;
            else vs2[n][hd] = s;
        }
        __syncthreads();
        // scores
        if (t < Nq * Nq) {
            int n = t / Nq, m = t - (t / Nq) * Nq;
            float s = 0.f;
#pragma unroll
            for (int hd = 0; hd < HDq; hd++) s += qs[n][hd] * ks2[m][hd];
            sm[n][m] = s * 0.125f;
        }
        __syncthreads();
        // softmax per row
        if (t < Nq) {
            float mx = -1e30f;
#pragma unroll
            for (int m = 0; m < Nq; m++) mx = fmaxf(mx, sm[t][m]);
            float ssum = 0.f;
#pragma unroll
            for (int m = 0; m < Nq; m++) {
                float e = expf(sm[t][m] - mx);
                ssum += e;
                sm[t][m] = e;
            }
            float r = 1.f / ssum;
#pragma unroll
            for (int m = 0; m < Nq; m++) sm[t][m] *= r;
        }
        __syncthreads();
        // o = attn @ v
        for (int idx = t; idx < Nq * HDq; idx += 512) {
            int n = idx >> 6, hd = idx & 63;
            float s = 0.f;
#pragma unroll
            for (int m = 0; m < Nq; m++) s += sm[n][m] * vs2[m][hd];
            oh[n][hd] = s;
        }
        __syncthreads();
        // proj partial: thread t owns output channel d=t
        const float4* pw = reinterpret_cast<const float4*>(projw + (size_t)t * DIMq + h * HDq);
#pragma unroll
        for (int c4 = 0; c4 < HDq / 4; c4++) {
            float4 wv = pw[c4];
#pragma unroll
            for (int n = 0; n < Nq; n++)
                acc[n] += oh[n][4 * c4] * wv.x + oh[n][4 * c4 + 1] * wv.y +
                          oh[n][4 * c4 + 2] * wv.z + oh[n][4 * c4 + 3] * wv.w;
        }
    }

    const float pb = projb[t];
#pragma unroll
    for (int n = 0; n < Nq; n++)
        out[((size_t)b * Nq + n) * DIMq + t] = xp[n] + acc[n] + pb;
}

extern "C" void kernel_launch(void* const* d_in, const int* in_sizes, int n_in,
                              void* d_out, int out_size, void* d_ws, size_t ws_size,
                              hipStream_t stream) {
    const float* x = (const float*)d_in[0];
    const float* adj = (const float*)d_in[1];
    const float* adj2 = (const float*)d_in[2];
    const float* W = (const float*)d_in[3];
    const float* Mg = (const float*)d_in[4];
    const float* gbias = (const float*)d_in[5];
    const float* bng = (const float*)d_in[6];
    const float* bnb = (const float*)d_in[7];
    const float* pos = (const float*)d_in[8];
    const float* lng = (const float*)d_in[9];
    const float* lnb = (const float*)d_in[10];
    const float* qkvw = (const float*)d_in[11];
    const float* projw = (const float*)d_in[12];
    const float* projb = (const float*)d_in[13];
    float* ws = (float*)d_ws;
    float* out = (float*)d_out;

    k_prep<<<1, 512, 0, stream>>>(adj, adj2, ws);
    k_stats<<<256, 512, 0, stream>>>(x, W, Mg, gbias, ws);
    k_finalize<<<1, 512, 0, stream>>>(bng, bnb, ws);
    k_main<<<Bq, 512, 0, stream>>>(x, W, Mg, gbias, pos, lng, lnb, qkvw, projw, projb, ws, out);
}

// Round 2
// 1589.058 us; speedup vs baseline: 15.3983x; 15.3983x over previous
//
#include <hip/hip_runtime.h>

typedef unsigned short ushort;
typedef __bf16 bf16x8 __attribute__((ext_vector_type(8)));
typedef float f32x4 __attribute__((ext_vector_type(4)));

#define Bq 4096
#define Nq 17
#define DIMq 512
#define EPSq 1e-5f

__device__ inline ushort f2bf(float f) {
    unsigned u = __builtin_bit_cast(unsigned, f);
    u += 0x7fff + ((u >> 16) & 1);
    return (ushort)(u >> 16);
}

__device__ inline f32x4 mfma16(bf16x8 a, bf16x8 b, f32x4 c) {
    return __builtin_amdgcn_mfma_f32_16x16x32_bf16(a, b, c, 0, 0, 0);
}

// ws layout: [0,289) A_sym | [512,1024) sum | [1024,1536) sumsq |
// [1536,2048) bn scale | [2048,2560) bn shift |
// byte 16384: wqkv bf16 (1536*512) | byte 1589248: wproj bf16 (512*512)

__global__ void k_prep(const float* __restrict__ adj, const float* __restrict__ adj2,
                       float* __restrict__ ws) {
    int t = threadIdx.x;
    if (t < Nq * Nq) {
        int n = t / Nq, m = t % Nq;
        ws[t] = 0.5f * ((adj[n * Nq + m] + adj2[n * Nq + m]) +
                        (adj[m * Nq + n] + adj2[m * Nq + n]));
    }
    ws[512 + t] = 0.f;
    ws[1024 + t] = 0.f;
}

__global__ __launch_bounds__(512) void k_stats(
    const float* __restrict__ x, const float* __restrict__ W,
    const float* __restrict__ Mg, const float* __restrict__ gbias,
    float* __restrict__ ws) {
    __shared__ float As[Nq * Nq];
    __shared__ float xs[2 * Nq];
    const int t = threadIdx.x;
    if (t < Nq * Nq) As[t] = ws[t];
    const float W00 = W[t], W01 = W[DIMq + t], W10 = W[2 * DIMq + t], W11 = W[3 * DIMq + t];
    const float gb = gbias[t];
    float Mr[Nq];
#pragma unroll
    for (int m = 0; m < Nq; m++) Mr[m] = Mg[m * DIMq + t];
    float sum = 0.f, sq = 0.f;
    for (int i = 0; i < 16; i++) {
        int b = blockIdx.x * 16 + i;
        __syncthreads();
        if (t < 2 * Nq) xs[t] = x[b * 2 * Nq + t];
        __syncthreads();
        float u[Nq];
#pragma unroll
        for (int m = 0; m < Nq; m++)
            u[m] = Mr[m] * (xs[2 * m] * W10 + xs[2 * m + 1] * W11);
#pragma unroll
        for (int n = 0; n < Nq; n++) {
            float S = gb;
#pragma unroll
            for (int m = 0; m < Nq; m++) S += As[n * Nq + m] * u[m];
            float dgn = Mr[n] * (xs[2 * n] * W00 + xs[2 * n + 1] * W01);
            float ov = S + As[n * Nq + n] * (dgn - u[n]);
            sum += ov;
            sq += ov * ov;
        }
    }
    atomicAdd(&ws[512 + t], sum);
    atomicAdd(&ws[1024 + t], sq);
}

__global__ void k_finalize(const float* __restrict__ bn_gamma,
                           const float* __restrict__ bn_beta,
                           float* __restrict__ ws) {
    int t = threadIdx.x;
    const float inv = 1.0f / (float)(Bq * Nq);
    float mean = ws[512 + t] * inv;
    float var = ws[1024 + t] * inv - mean * mean;
    float rstd = 1.0f / sqrtf(var + EPSq);
    float sc = bn_gamma[t] * rstd;
    ws[1536 + t] = sc;
    ws[2048 + t] = bn_beta[t] - mean * sc;
}

__global__ void k_wconv(const float* __restrict__ qkvw, const float* __restrict__ projw,
                        ushort* __restrict__ wq, ushort* __restrict__ wp) {
    int i = blockIdx.x * 256 + threadIdx.x;
    if (i < 1536 * 512) wq[i] = f2bf(qkvw[i]);
    if (i < 512 * 512) wp[i] = f2bf(projw[i]);
}

__global__ __launch_bounds__(256, 2) void k_fused(
    const float* __restrict__ x, const float* __restrict__ W,
    const float* __restrict__ Mg, const float* __restrict__ gbias,
    const float* __restrict__ pos, const float* __restrict__ lng,
    const float* __restrict__ lnb, const float* __restrict__ projb,
    const float* __restrict__ ws, const ushort* __restrict__ wq,
    const ushort* __restrict__ wp, float* __restrict__ out) {
    __shared__ float smem[17508];
    float* As = smem;                       // 289
    float* xs = smem + 289;                 // 34
    float* muv = smem + 324;                // 17
    float* rsv = smem + 341;                // 17
    float* stats = smem + 358;              // 34
    float* red = smem + 392;                // 4*34
    ushort* xnS = (ushort*)(smem + 544);    // 32 rows * 512 bf16, XOR-swizzled
    float* U = smem + 8736;                 // union region
    float* qS = U;                          // [17][68]
    float* kS = U + 1156;
    float* vS = U + 2312;
    float* smx = U + 3468;                  // [17][18]
    ushort* oS = (ushort*)(U + 3776);       // 32 rows * 64 bf16, XOR-swizzled
    float* pAccS = U;                       // [17][516] (aliases phase-1 bufs)

    const int t = threadIdx.x;
    const int b = blockIdx.x;
    const int lane = t & 63, w = t >> 6;

    // zero padded rows (17..31) of xnS and oS once
    for (int i = 17 * 512 + t; i < 32 * 512; i += 256) xnS[i] = 0;
    for (int i = 17 * 64 + t; i < 32 * 64; i += 256) oS[i] = 0;
    for (int i = t; i < 289; i += 256) As[i] = ws[i];
    if (t < 34) xs[t] = x[b * 34 + t];

    float W00[2], W01[2], W10[2], W11[2], gb2[2], bsc[2], bsh[2], lg[2], lb[2], pb[2];
#pragma unroll
    for (int j = 0; j < 2; j++) {
        int c = t + j * 256;
        W00[j] = W[c]; W01[j] = W[512 + c]; W10[j] = W[1024 + c]; W11[j] = W[1536 + c];
        gb2[j] = gbias[c]; bsc[j] = ws[1536 + c]; bsh[j] = ws[2048 + c];
        lg[j] = lng[c]; lb[j] = lnb[c]; pb[j] = projb[c];
    }
    __syncthreads();

    // --- graph conv + BN + relu + pos (residual xp in regs) ---
    float xp[17][2];
    {
        float u_[17][2], dg_[17][2];
#pragma unroll
        for (int m = 0; m < 17; m++) {
            float x0 = xs[2 * m], x1 = xs[2 * m + 1];
#pragma unroll
            for (int j = 0; j < 2; j++) {
                float Mv = Mg[m * 512 + t + j * 256];
                u_[m][j] = Mv * (x0 * W10[j] + x1 * W11[j]);
                dg_[m][j] = Mv * (x0 * W00[j] + x1 * W01[j]);
            }
        }
#pragma unroll
        for (int n = 0; n < 17; n++) {
            float S0 = gb2[0], S1 = gb2[1];
#pragma unroll
            for (int m = 0; m < 17; m++) {
                float a = As[n * 17 + m];
                S0 += a * u_[m][0];
                S1 += a * u_[m][1];
            }
            float ad = As[n * 17 + n];
            float ov0 = S0 + ad * (dg_[n][0] - u_[n][0]);
            float ov1 = S1 + ad * (dg_[n][1] - u_[n][1]);
            xp[n][0] = fmaxf(ov0 * bsc[0] + bsh[0], 0.f) + pos[n * 512 + t];
            xp[n][1] = fmaxf(ov1 * bsc[1] + bsh[1], 0.f) + pos[n * 512 + t + 256];
        }
    }
    // --- LayerNorm stats ---
#pragma unroll
    for (int n = 0; n < 17; n++) {
        float a = xp[n][0] + xp[n][1];
        float q2 = xp[n][0] * xp[n][0] + xp[n][1] * xp[n][1];
#pragma unroll
        for (int off = 32; off; off >>= 1) {
            a += __shfl_xor(a, off);
            q2 += __shfl_xor(q2, off);
        }
        if (lane == 0) { red[w * 34 + n] = a; red[w * 34 + 17 + n] = q2; }
    }
    __syncthreads();
    if (t < 34) stats[t] = red[t] + red[34 + t] + red[68 + t] + red[102 + t];
    __syncthreads();
    if (t < 17) {
        float mu = stats[t] * (1.f / 512.f);
        float var = stats[17 + t] * (1.f / 512.f) - mu * mu;
        muv[t] = mu;
        rsv[t] = 1.f / sqrtf(var + EPSq);
    }
    __syncthreads();
#pragma unroll
    for (int n = 0; n < 17; n++) {
#pragma unroll
        for (int j = 0; j < 2; j++) {
            int c = t + j * 256;
            float xnv = (xp[n][j] - muv[n]) * rsv[n] * lg[j] + lb[j];
            int sb = (2 * c) ^ ((n & 7) << 4);
            xnS[n * 512 + (sb >> 1)] = f2bf(xnv);
        }
    }
    __syncthreads();

    // --- per-head: qkv MFMA -> attention (fp32) -> proj MFMA ---
    f32x4 pA[2][8];
#pragma unroll
    for (int mt = 0; mt < 2; mt++)
#pragma unroll
        for (int jn = 0; jn < 8; jn++) pA[mt][jn] = (f32x4){0.f, 0.f, 0.f, 0.f};

    const int l15 = lane & 15, g = lane >> 4;
    const char* xnC = (const char*)xnS;
    const char* oC = (const char*)oS;
    const int arow0 = l15, arow1 = 16 + l15;
    const int asw0 = (arow0 & 7) << 4, asw1 = (arow1 & 7) << 4;

    for (int h = 0; h < 8; h++) {
        // qkv GEMM: wave w owns N-tiles {w*3, w*3+1, w*3+2} of 12 (3 which x 4 nt)
        f32x4 qa[2][3];
#pragma unroll
        for (int mt = 0; mt < 2; mt++)
#pragma unroll
            for (int jt = 0; jt < 3; jt++) qa[mt][jt] = (f32x4){0.f, 0.f, 0.f, 0.f};
        const ushort* bb[3];
        int whichv[3], ntlv[3];
#pragma unroll
        for (int jt = 0; jt < 3; jt++) {
            int tid = w * 3 + jt;
            int which = tid >> 2, ntl = tid & 3;
            whichv[jt] = which; ntlv[jt] = ntl;
            int d = which * 512 + h * 64 + ntl * 16 + l15;
            bb[jt] = wq + d * 512 + g * 8;
        }
#pragma unroll
        for (int ks = 0; ks < 16; ks++) {
            int colb = (ks << 6) | (g << 4);
            bf16x8 a0 = *(const bf16x8*)(xnC + arow0 * 1024 + (colb ^ asw0));
            bf16x8 a1 = *(const bf16x8*)(xnC + arow1 * 1024 + (colb ^ asw1));
            bf16x8 b0 = *(const bf16x8*)(bb[0] + ks * 32);
            bf16x8 b1 = *(const bf16x8*)(bb[1] + ks * 32);
            bf16x8 b2 = *(const bf16x8*)(bb[2] + ks * 32);
            qa[0][0] = mfma16(a0, b0, qa[0][0]);
            qa[1][0] = mfma16(a1, b0, qa[1][0]);
            qa[0][1] = mfma16(a0, b1, qa[0][1]);
            qa[1][1] = mfma16(a1, b1, qa[1][1]);
            qa[0][2] = mfma16(a0, b2, qa[0][2]);
            qa[1][2] = mfma16(a1, b2, qa[1][2]);
        }
#pragma unroll
        for (int jt = 0; jt < 3; jt++) {
            float* dst = whichv[jt] == 0 ? qS : (whichv[jt] == 1 ? kS : vS);
            int colb = ntlv[jt] * 16 + l15;
#pragma unroll
            for (int mt = 0; mt < 2; mt++)
#pragma unroll
                for (int r = 0; r < 4; r++) {
                    int row = mt * 16 + g * 4 + r;
                    if (row < 17) dst[row * 68 + colb] = qa[mt][jt][r];
                }
        }
        __syncthreads();
        // scores
        for (int idx = t; idx < 289; idx += 256) {
            int n = idx / 17, m = idx - n * 17;
            const float* qr = qS + n * 68;
            const float* kr = kS + m * 68;
            float s = 0.f;
#pragma unroll
            for (int hd = 0; hd < 64; hd++) s += qr[hd] * kr[hd];
            smx[n * 18 + m] = s * 0.125f;
        }
        __syncthreads();
        if (t < 17) {
            float mx = -1e30f;
#pragma unroll
            for (int m = 0; m < 17; m++) mx = fmaxf(mx, smx[t * 18 + m]);
            float ss = 0.f;
#pragma unroll
            for (int m = 0; m < 17; m++) {
                float e = expf(smx[t * 18 + m] - mx);
                ss += e;
                smx[t * 18 + m] = e;
            }
            float r = 1.f / ss;
#pragma unroll
            for (int m = 0; m < 17; m++) smx[t * 18 + m] *= r;
        }
        __syncthreads();
        for (int idx = t; idx < 1088; idx += 256) {
            int n = idx >> 6, hd = idx & 63;
            float s = 0.f;
#pragma unroll
            for (int m = 0; m < 17; m++) s += smx[n * 18 + m] * vS[m * 68 + hd];
            int sb = (2 * hd) ^ ((n & 7) << 4);
            oS[n * 64 + (sb >> 1)] = f2bf(s);
        }
        __syncthreads();
        // proj partial: o_h [17,64] x projw[:, h*64:+64]^T, acc in regs
#pragma unroll
        for (int ks = 0; ks < 2; ks++) {
            int colb = (ks << 6) | (g << 4);
            bf16x8 a0 = *(const bf16x8*)(oC + arow0 * 128 + (colb ^ asw0));
            bf16x8 a1 = *(const bf16x8*)(oC + arow1 * 128 + (colb ^ asw1));
            const ushort* wpb = wp + h * 64 + ks * 32 + g * 8;
#pragma unroll
            for (int jn = 0; jn < 8; jn++) {
                int d = (w * 8 + jn) * 16 + l15;
                bf16x8 bfr = *(const bf16x8*)(wpb + d * 512);
                pA[0][jn] = mfma16(a0, bfr, pA[0][jn]);
                pA[1][jn] = mfma16(a1, bfr, pA[1][jn]);
            }
        }
        __syncthreads();
    }
    // dump proj acc -> LDS, add residual, write out
#pragma unroll
    for (int mt = 0; mt < 2; mt++)
#pragma unroll
        for (int jn = 0; jn < 8; jn++) {
            int colb = (w * 8 + jn) * 16 + l15;
#pragma unroll
            for (int r = 0; r < 4; r++) {
                int row = mt * 16 + g * 4 + r;
                if (row < 17) pAccS[row * 516 + colb] = pA[mt][jn][r];
            }
        }
    __syncthreads();
#pragma unroll
    for (int n = 0; n < 17; n++) {
        size_t o0 = ((size_t)b * 17 + n) * 512;
        out[o0 + t] = xp[n][0] + pAccS[n * 516 + t] + pb[0];
        out[o0 + t + 256] = xp[n][1] + pAccS[n * 516 + t + 256] + pb[1];
    }
}

extern "C" void kernel_launch(void* const* d_in, const int* in_sizes, int n_in,
                              void* d_out, int out_size, void* d_ws, size_t ws_size,
                              hipStream_t stream) {
    const float* x = (const float*)d_in[0];
    const float* adj = (const float*)d_in[1];
    const float* adj2 = (const float*)d_in[2];
    const float* W = (const float*)d_in[3];
    const float* Mg = (const float*)d_in[4];
    const float* gbias = (const float*)d_in[5];
    const float* bng = (const float*)d_in[6];
    const float* bnb = (const float*)d_in[7];
    const float* pos = (const float*)d_in[8];
    const float* lng = (const float*)d_in[9];
    const float* lnb = (const float*)d_in[10];
    const float* qkvw = (const float*)d_in[11];
    const float* projw = (const float*)d_in[12];
    const float* projb = (const float*)d_in[13];
    float* ws = (float*)d_ws;
    float* out = (float*)d_out;
    ushort* wq = (ushort*)((char*)d_ws + 16384);
    ushort* wp = (ushort*)((char*)d_ws + 16384 + 1536 * 512 * 2);

    k_prep<<<1, 512, 0, stream>>>(adj, adj2, ws);
    k_stats<<<256, 512, 0, stream>>>(x, W, Mg, gbias, ws);
    k_finalize<<<1, 512, 0, stream>>>(bng, bnb, ws);
    k_wconv<<<3072, 256, 0, stream>>>(qkvw, projw, wq, wp);
    k_fused<<<Bq, 256, 0, stream>>>(x, W, Mg, gbias, pos, lng, lnb, projb,
                                    ws, wq, wp, out);
}

// Round 3
// 1511.212 us; speedup vs baseline: 16.1915x; 1.0515x over previous
//
#include <hip/hip_runtime.h>

typedef unsigned short ushort;
typedef unsigned int uint;
typedef __bf16 bf16x8 __attribute__((ext_vector_type(8)));
typedef float f32x4 __attribute__((ext_vector_type(4)));
typedef int i32x4 __attribute__((ext_vector_type(4)));

#define Bq 4096
#define Nq 17
#define DIMq 512
#define EPSq 1e-5f

__device__ inline ushort f2bf(float f) {
    unsigned u = __builtin_bit_cast(unsigned, f);
    u += 0x7fff + ((u >> 16) & 1);
    return (ushort)(u >> 16);
}
__device__ inline float bfs(ushort u) { return __builtin_bit_cast(float, (uint)u << 16); }
__device__ inline float bflo(uint u) { return __builtin_bit_cast(float, u << 16); }
__device__ inline float bfhi(uint u) { return __builtin_bit_cast(float, u & 0xffff0000u); }

__device__ inline f32x4 mfma16(bf16x8 a, bf16x8 b, f32x4 c) {
    return __builtin_amdgcn_mfma_f32_16x16x32_bf16(a, b, c, 0, 0, 0);
}

// ws: [0,289) A_sym | [512,1024) sum | [1024,1536) sumsq | [1536,2048) bn scale |
// [2048,2560) bn shift | byte 16384: wq bf16 1536x512 | byte 1589248: wp bf16 512x512

__global__ void k_prep(const float* __restrict__ adj, const float* __restrict__ adj2,
                       float* __restrict__ ws) {
    int t = threadIdx.x;
    if (t < Nq * Nq) {
        int n = t / Nq, m = t % Nq;
        ws[t] = 0.5f * ((adj[n * Nq + m] + adj2[n * Nq + m]) +
                        (adj[m * Nq + n] + adj2[m * Nq + n]));
    }
    ws[512 + t] = 0.f;
    ws[1024 + t] = 0.f;
}

__global__ __launch_bounds__(512) void k_stats(
    const float* __restrict__ x, const float* __restrict__ W,
    const float* __restrict__ Mg, const float* __restrict__ gbias,
    float* __restrict__ ws) {
    __shared__ float As[Nq * Nq];
    __shared__ float xs[2 * Nq];
    const int t = threadIdx.x;
    if (t < Nq * Nq) As[t] = ws[t];
    const float W00 = W[t], W01 = W[DIMq + t], W10 = W[2 * DIMq + t], W11 = W[3 * DIMq + t];
    const float gb = gbias[t];
    float Mr[Nq];
#pragma unroll
    for (int m = 0; m < Nq; m++) Mr[m] = Mg[m * DIMq + t];
    float sum = 0.f, sq = 0.f;
    for (int i = 0; i < 16; i++) {
        int b = blockIdx.x * 16 + i;
        __syncthreads();
        if (t < 2 * Nq) xs[t] = x[b * 2 * Nq + t];
        __syncthreads();
        float u[Nq];
#pragma unroll
        for (int m = 0; m < Nq; m++)
            u[m] = Mr[m] * (xs[2 * m] * W10 + xs[2 * m + 1] * W11);
#pragma unroll
        for (int n = 0; n < Nq; n++) {
            float S = gb;
#pragma unroll
            for (int m = 0; m < Nq; m++) S += As[n * Nq + m] * u[m];
            float dgn = Mr[n] * (xs[2 * n] * W00 + xs[2 * n + 1] * W01);
            float ov = S + As[n * Nq + n] * (dgn - u[n]);
            sum += ov;
            sq += ov * ov;
        }
    }
    atomicAdd(&ws[512 + t], sum);
    atomicAdd(&ws[1024 + t], sq);
}

__global__ void k_finalize(const float* __restrict__ bn_gamma,
                           const float* __restrict__ bn_beta,
                           float* __restrict__ ws) {
    int t = threadIdx.x;
    const float inv = 1.0f / (float)(Bq * Nq);
    float mean = ws[512 + t] * inv;
    float var = ws[1024 + t] * inv - mean * mean;
    float rstd = 1.0f / sqrtf(var + EPSq);
    float sc = bn_gamma[t] * rstd;
    ws[1536 + t] = sc;
    ws[2048 + t] = bn_beta[t] - mean * sc;
}

__global__ void k_wconv(const float* __restrict__ qkvw, const float* __restrict__ projw,
                        ushort* __restrict__ wq, ushort* __restrict__ wp) {
    int i = blockIdx.x * 256 + threadIdx.x;
    if (i < 1536 * 512) wq[i] = f2bf(qkvw[i]);
    if (i < 512 * 512) wp[i] = f2bf(projw[i]);
}

// LDS layout (bytes):
//   0      : xn   bf16 [17][512] swizzled     (17408)
//   17408  : q / o bf16 [17][512] swizzled    (17408)
//   34816  : k    bf16 [17][512] swizzled     (17408)  [phase-1 misc aliases head]
//   52224  : v    bf16 [17][512] swizzled     (17408)
//   69632  : P per-wave [2][17][18] bf16      (4 * 1232)
//   pAcc f32 [17][512] aliases k+v after attention.
__global__ __launch_bounds__(256, 2) void k_fused(
    const float* __restrict__ x, const float* __restrict__ W,
    const float* __restrict__ Mg, const float* __restrict__ gbias,
    const float* __restrict__ pos, const float* __restrict__ lng,
    const float* __restrict__ lnb, const float* __restrict__ projb,
    const float* __restrict__ ws, const ushort* __restrict__ wq,
    const ushort* __restrict__ wp, float* __restrict__ out) {
    __shared__ __align__(16) char S[74560];
    char* xnC = S;
    char* qoC = S + 17408;
    char* kC = S + 34816;
    char* vC = S + 52224;
    char* pC = S + 69632;
    // phase-1 scratch aliases kC (dead before phase 2 writes k there)
    float* As = (float*)kC;          // 289
    float* xs = As + 289;            // 34
    float* red = xs + 34;            // 136
    float* stats = red + 136;        // 34
    float* muv = stats + 34;         // 17
    float* rsv = muv + 17;           // 17

    const int t = threadIdx.x;
    const int b = blockIdx.x;
    const int lane = t & 63, w = t >> 6;
    const int l15 = lane & 15, g = lane >> 4;
    const int aswz0 = (l15 & 7) << 4;

    // zero this wave's P buffer (pad col 17 must stay 0)
    for (int i = lane; i < 77; i += 64)
        ((i32x4*)(pC + w * 1232))[i] = (i32x4){0, 0, 0, 0};

    for (int i = t; i < 289; i += 256) As[i] = ws[i];
    if (t < 34) xs[t] = x[b * 34 + t];

    float W00[2], W01[2], W10[2], W11[2], gb2[2], bsc[2], bsh[2], lg[2], lb[2], pb[2];
#pragma unroll
    for (int j = 0; j < 2; j++) {
        int c = t + j * 256;
        W00[j] = W[c]; W01[j] = W[512 + c]; W10[j] = W[1024 + c]; W11[j] = W[1536 + c];
        gb2[j] = gbias[c]; bsc[j] = ws[1536 + c]; bsh[j] = ws[2048 + c];
        lg[j] = lng[c]; lb[j] = lnb[c]; pb[j] = projb[c];
    }
    __syncthreads();  // (1) As/xs ready

    // ---- phase 1: graph conv + BN + relu + pos (residual xp in regs) ----
    float xp[17][2];
    {
        float u_[17][2], dg_[17][2];
#pragma unroll
        for (int m = 0; m < 17; m++) {
            float x0 = xs[2 * m], x1 = xs[2 * m + 1];
#pragma unroll
            for (int j = 0; j < 2; j++) {
                float Mv = Mg[m * 512 + t + j * 256];
                u_[m][j] = Mv * (x0 * W10[j] + x1 * W11[j]);
                dg_[m][j] = Mv * (x0 * W00[j] + x1 * W01[j]);
            }
        }
#pragma unroll
        for (int n = 0; n < 17; n++) {
            float S0 = gb2[0], S1 = gb2[1];
#pragma unroll
            for (int m = 0; m < 17; m++) {
                float a = As[n * 17 + m];
                S0 += a * u_[m][0];
                S1 += a * u_[m][1];
            }
            float ad = As[n * 17 + n];
            float ov0 = S0 + ad * (dg_[n][0] - u_[n][0]);
            float ov1 = S1 + ad * (dg_[n][1] - u_[n][1]);
            xp[n][0] = fmaxf(ov0 * bsc[0] + bsh[0], 0.f) + pos[n * 512 + t];
            xp[n][1] = fmaxf(ov1 * bsc[1] + bsh[1], 0.f) + pos[n * 512 + t + 256];
        }
    }
    // ---- LayerNorm stats ----
#pragma unroll
    for (int n = 0; n < 17; n++) {
        float a = xp[n][0] + xp[n][1];
        float q2 = xp[n][0] * xp[n][0] + xp[n][1] * xp[n][1];
#pragma unroll
        for (int off = 32; off; off >>= 1) {
            a += __shfl_xor(a, off);
            q2 += __shfl_xor(q2, off);
        }
        if (lane == 0) { red[w * 34 + n] = a; red[w * 34 + 17 + n] = q2; }
    }
    __syncthreads();  // (2)
    if (t < 34) stats[t] = red[t] + red[34 + t] + red[68 + t] + red[102 + t];
    __syncthreads();  // (3)
    if (t < 17) {
        float mu = stats[t] * (1.f / 512.f);
        float var = stats[17 + t] * (1.f / 512.f) - mu * mu;
        muv[t] = mu;
        rsv[t] = 1.f / sqrtf(var + EPSq);
    }
    __syncthreads();  // (4)
    {
        ushort* xnU = (ushort*)xnC;
#pragma unroll
        for (int n = 0; n < 17; n++) {
            int sw = (n & 7) << 4;
#pragma unroll
            for (int j = 0; j < 2; j++) {
                int c = t + j * 256;
                float xnv = (xp[n][j] - muv[n]) * rsv[n] * lg[j] + lb[j];
                xnU[(n * 1024 + ((2 * c) ^ sw)) >> 1] = f2bf(xnv);
            }
        }
    }
    __syncthreads();  // (5) xn ready; phase-1 scratch dead

    // ---- phase 2: qkv GEMM for all heads; wave w owns N-tiles [24w, 24w+24) ----
    {
        const char* a0b = xnC + l15 * 1024;
        const char* a1b = xnC + 16 * 1024;
        for (int c = 0; c < 4; c++) {
            int tbase = w * 24 + c * 6;
            f32x4 acc0[6], acc1[6];
#pragma unroll
            for (int j = 0; j < 6; j++) {
                acc0[j] = (f32x4){0.f, 0.f, 0.f, 0.f};
                acc1[j] = (f32x4){0.f, 0.f, 0.f, 0.f};
            }
            const ushort* bp[6];
#pragma unroll
            for (int j = 0; j < 6; j++)
                bp[j] = wq + (size_t)((tbase + j) * 16 + l15) * 512 + g * 8;
#pragma unroll 4
            for (int ks = 0; ks < 16; ks++) {
                int colb = ks * 64 + g * 16;
                bf16x8 a0 = *(const bf16x8*)(a0b + (colb ^ aswz0));
                bf16x8 a1 = *(const bf16x8*)(a1b + colb);
#pragma unroll
                for (int j = 0; j < 6; j++) {
                    bf16x8 bv = *(const bf16x8*)(bp[j] + ks * 32);
                    acc0[j] = mfma16(a0, bv, acc0[j]);
                    acc1[j] = mfma16(a1, bv, acc1[j]);
                }
            }
#pragma unroll
            for (int j = 0; j < 6; j++) {
                int t_ = tbase + j;
                int which = t_ >> 5;
                int col = (t_ & 31) * 16 + l15;
                char* dst = which == 0 ? qoC : (which == 1 ? kC : vC);
#pragma unroll
                for (int r = 0; r < 4; r++) {
                    int n = g * 4 + r;
                    *(ushort*)(dst + n * 1024 + ((2 * col) ^ ((n & 7) << 4))) = f2bf(acc0[j][r]);
                }
                if (g == 0)
                    *(ushort*)(dst + 16 * 1024 + 2 * col) = f2bf(acc1[j][0]);
            }
        }
    }
    __syncthreads();  // (6) q,k,v ready

    // ---- phase 3a: scores + softmax (per wave, heads 2w, 2w+1) ----
    ushort* pw16 = (ushort*)(pC + w * 1232);
#pragma unroll
    for (int hh = 0; hh < 2; hh++) {
        int hb = (2 * w + hh) * 128;
        f32x4 sa[2][2];
        sa[0][0] = (f32x4){0.f, 0.f, 0.f, 0.f}; sa[0][1] = sa[0][0];
        sa[1][0] = sa[0][0]; sa[1][1] = sa[0][0];
#pragma unroll
        for (int ks2 = 0; ks2 < 2; ks2++) {
            int cb = hb + ks2 * 64 + g * 16;
            bf16x8 qa0 = *(const bf16x8*)(qoC + l15 * 1024 + (cb ^ aswz0));
            bf16x8 qa1 = *(const bf16x8*)(qoC + 16 * 1024 + cb);
            bf16x8 kb0 = *(const bf16x8*)(kC + l15 * 1024 + (cb ^ aswz0));
            bf16x8 kb1 = *(const bf16x8*)(kC + 16 * 1024 + cb);
            sa[0][0] = mfma16(qa0, kb0, sa[0][0]);
            sa[1][0] = mfma16(qa1, kb0, sa[1][0]);
            sa[0][1] = mfma16(qa0, kb1, sa[0][1]);
            sa[1][1] = mfma16(qa1, kb1, sa[1][1]);
        }
#pragma unroll
        for (int mt = 0; mt < 2; mt++)
#pragma unroll
            for (int r = 0; r < 4; r++) {
                float sc0 = sa[mt][0][r] * 0.125f;
                float sc1v = sa[mt][1][r] * 0.125f;
                float sc1 = (l15 == 0) ? sc1v : -1e30f;
                float mx = fmaxf(sc0, sc1);
#pragma unroll
                for (int off = 1; off < 16; off <<= 1) mx = fmaxf(mx, __shfl_xor(mx, off));
                float e0 = __expf(sc0 - mx);
                float e1 = (l15 == 0) ? __expf(sc1v - mx) : 0.f;
                float sm = e0 + e1;
#pragma unroll
                for (int off = 1; off < 16; off <<= 1) sm += __shfl_xor(sm, off);
                float ri = 1.f / sm;
                int n = mt * 16 + g * 4 + r;
                if (n < 17) {
                    pw16[hh * 306 + n * 18 + l15] = f2bf(e0 * ri);
                    if (l15 == 0) pw16[hh * 306 + n * 18 + 16] = f2bf(e1 * ri);
                }
            }
    }
    __syncthreads();  // (7) all score reads of q done; o may overwrite q

    // ---- phase 3b: PV in VALU (per wave), write o over q region ----
#pragma unroll
    for (int hh = 0; hh < 2; hh++) {
        int hb = (2 * w + hh) * 128;
        float vv[18];
        vv[17] = 0.f;
#pragma unroll
        for (int m = 0; m < 17; m++)
            vv[m] = bfs(*(const ushort*)(vC + m * 1024 + ((hb + 2 * lane) ^ ((m & 7) << 4))));
        const uint* pr = (const uint*)(pC + w * 1232 + hh * 612);
#pragma unroll
        for (int n = 0; n < 17; n++) {
            float o_ = 0.f;
#pragma unroll
            for (int q = 0; q < 9; q++) {
                uint p2 = pr[n * 9 + q];
                o_ += bflo(p2) * vv[2 * q] + bfhi(p2) * vv[2 * q + 1];
            }
            *(ushort*)(qoC + n * 1024 + ((hb + 2 * lane) ^ ((n & 7) << 4))) = f2bf(o_);
        }
    }
    __syncthreads();  // (8) o complete

    // ---- phase 4: proj GEMM; wave w owns out cols [128w, 128w+128) ----
    {
        f32x4 pa0[8], pa1[8];
#pragma unroll
        for (int nt = 0; nt < 8; nt++) {
            pa0[nt] = (f32x4){0.f, 0.f, 0.f, 0.f};
            pa1[nt] = (f32x4){0.f, 0.f, 0.f, 0.f};
        }
        const ushort* wpB[8];
#pragma unroll
        for (int nt = 0; nt < 8; nt++)
            wpB[nt] = wp + (size_t)(w * 128 + nt * 16 + l15) * 512 + g * 8;
#pragma unroll 4
        for (int ks = 0; ks < 16; ks++) {
            int colb = ks * 64 + g * 16;
            bf16x8 a0 = *(const bf16x8*)(qoC + l15 * 1024 + (colb ^ aswz0));
            bf16x8 a1 = *(const bf16x8*)(qoC + 16 * 1024 + colb);
#pragma unroll
            for (int nt = 0; nt < 8; nt++) {
                bf16x8 bv = *(const bf16x8*)(wpB[nt] + ks * 32);
                pa0[nt] = mfma16(a0, bv, pa0[nt]);
                pa1[nt] = mfma16(a1, bv, pa1[nt]);
            }
        }
        float* pAcc = (float*)kC;  // [17][512], aliases k+v (dead)
#pragma unroll
        for (int nt = 0; nt < 8; nt++) {
            int col = w * 128 + nt * 16 + l15;
#pragma unroll
            for (int r = 0; r < 4; r++) {
                int n = g * 4 + r;
                pAcc[n * 512 + col] = pa0[nt][r];
            }
            if (g == 0) pAcc[16 * 512 + col] = pa1[nt][0];
        }
    }
    __syncthreads();  // (9)
    {
        const float* pAcc = (const float*)kC;
#pragma unroll
        for (int n = 0; n < 17; n++) {
            size_t o0 = ((size_t)b * 17 + n) * 512;
            out[o0 + t] = xp[n][0] + pAcc[n * 512 + t] + pb[0];
            out[o0 + t + 256] = xp[n][1] + pAcc[n * 512 + t + 256] + pb[1];
        }
    }
}

extern "C" void kernel_launch(void* const* d_in, const int* in_sizes, int n_in,
                              void* d_out, int out_size, void* d_ws, size_t ws_size,
                              hipStream_t stream) {
    const float* x = (const float*)d_in[0];
    const float* adj = (const float*)d_in[1];
    const float* adj2 = (const float*)d_in[2];
    const float* W = (const float*)d_in[3];
    const float* Mg = (const float*)d_in[4];
    const float* gbias = (const float*)d_in[5];
    const float* bng = (const float*)d_in[6];
    const float* bnb = (const float*)d_in[7];
    const float* pos = (const float*)d_in[8];
    const float* lng = (const float*)d_in[9];
    const float* lnb = (const float*)d_in[10];
    const float* qkvw = (const float*)d_in[11];
    const float* projw = (const float*)d_in[12];
    const float* projb = (const float*)d_in[13];
    float* ws = (float*)d_ws;
    float* out = (float*)d_out;
    ushort* wq = (ushort*)((char*)d_ws + 16384);
    ushort* wp = (ushort*)((char*)d_ws + 16384 + 1536 * 512 * 2);

    k_prep<<<1, 512, 0, stream>>>(adj, adj2, ws);
    k_stats<<<256, 512, 0, stream>>>(x, W, Mg, gbias, ws);
    k_finalize<<<1, 512, 0, stream>>>(bng, bnb, ws);
    k_wconv<<<3072, 256, 0, stream>>>(qkvw, projw, wq, wp);
    k_fused<<<Bq, 256, 0, stream>>>(x, W, Mg, gbias, pos, lng, lnb, projb,
                                    ws, wq, wp, out);
}